// Round 6
// baseline (347.066 us; speedup 1.0000x reference)
//
#include <hip/hip_runtime.h>
#include <math.h>

// Problem constants (fixed shapes)
#define N_PTS 32768
#define C_DIM 128
#define K_NB  16
#define G_DIM 8

// Workspace float offsets
#define OF_PW     0          // 128*8  P @ Ww1 (fp32)
#define OF_STATQ  1024       // 256 (sum, sumsq) of q_lin
#define OF_STATK  1280       // 256
#define OF_STATG1 1536       // 256
#define OF_STATH  1792       // 16
#define OF_UMAXP  1808       // 4*128 encoded max(q_lin) per seg
#define OF_UMAXN  2320       // 4*128 encoded max(-q_lin) per seg  (zero region = 1024..2832, 1808 words)
// bf16 [n][k] operands, 16384 shorts = 8192 floats each
#define OF_WQT    4096
#define OF_WKT    12288
#define OF_WVT    20480
#define OF_WG1T   28672
#define OF_PTMIT  36864
#define OF_QW     65536      // N*8
#define OF_KW     327680     // N*8
#define OF_GATE   589824     // N*8
#define OF_G1     1048576    // N*128
#define OF_V      5242880    // N*128

typedef short bf16x8 __attribute__((ext_vector_type(8)));
typedef float f32x4  __attribute__((ext_vector_type(4)));

#define LSTR 136   // bf16 LDS row stride (272 B, 8B-aligned, conflict-benign)

__device__ __forceinline__ unsigned f2bf(float f) {
  unsigned u = __float_as_uint(f);
  return (u + 0x7fffu + ((u >> 16) & 1u)) >> 16;
}
__device__ __forceinline__ float bf2f(short s) {
  return __uint_as_float(((unsigned)(unsigned short)s) << 16);
}
__device__ __forceinline__ unsigned fenc(float f) {
  unsigned b = __float_as_uint(f);
  return (b & 0x80000000u) ? ~b : (b | 0x80000000u);
}
__device__ __forceinline__ float fdec(unsigned u) {
  unsigned b = (u & 0x80000000u) ? (u & 0x7fffffffu) : ~u;
  return __uint_as_float(b);
}
__device__ __forceinline__ bf16x8 pack_bf8(float4 a, float4 b) {
  bf16x8 r;
  r[0] = (short)f2bf(a.x); r[1] = (short)f2bf(a.y);
  r[2] = (short)f2bf(a.z); r[3] = (short)f2bf(a.w);
  r[4] = (short)f2bf(b.x); r[5] = (short)f2bf(b.y);
  r[6] = (short)f2bf(b.z); r[7] = (short)f2bf(b.w);
  return r;
}
__device__ __forceinline__ float fetch_asym(const float* M, int r, int c) {
  return (c > r) ? M[r*128 + c] : ((c < r) ? -M[c*128 + r] : 0.f);
}

// B-operand MFMA pass: out[nt] = af @ BT, BT bf16 [n][k] in global (L2-hot)
__device__ __forceinline__ void gemm8(const short* __restrict__ BT, const bf16x8* af,
                                      f32x4* out, int l15, int quad)
{
  #pragma unroll
  for (int nt = 0; nt < 8; ++nt) {
    f32x4 ac = {0.f, 0.f, 0.f, 0.f};
    #pragma unroll
    for (int ks = 0; ks < 4; ++ks) {
      bf16x8 bf = *(const bf16x8*)&BT[(nt*16 + l15)*128 + ks*32 + quad*8];
      ac = __builtin_amdgcn_mfma_f32_16x16x32_bf16(af[ks], bf, ac, 0, 0, 0);
    }
    out[nt] = ac;
  }
}

// ---------------------------------------------------------------------------
// cayley: ONE kernel for all preprocessing.
//  blocks 0..63  : Neumann-solve 2 columns of (I-S)^-1 (x <- e + S x, 16 iters;
//                  ||S||~0.23 -> trunc err ~1e-11). Emits PTmIT rows (bf16) and
//                  PW rows (fp32).  PTmIT[n][k] = PT[k][n]-d = 2 inv[k][n]-2d.
//                  PW[c][g] = 2 sum_j inv[j][c] Ww1[j][g] - Ww1[c][g].
//  blocks 64..79 : Wq/Wk/Wv/Wg1top -> bf16 transposed [n][k]
//  block  80     : zero the stats region
__global__ __launch_bounds__(256) void cayley(const float* __restrict__ Sp,
    const float* __restrict__ Ww1,
    const float* __restrict__ Wq, const float* __restrict__ Wk,
    const float* __restrict__ Wv, const float* __restrict__ Wg1,
    short* __restrict__ WqT, short* __restrict__ WkT,
    short* __restrict__ WvT, short* __restrict__ Wg1T,
    short* __restrict__ PTmIT, float* __restrict__ PW,
    float* __restrict__ statz)
{
  __shared__ short Ssh[128*LSTR];
  __shared__ float x0[128], x1[128];
  int bx = blockIdx.x, tid = threadIdx.x;
  if (bx >= 64) {
    if (bx < 80) {
      int idx = bx - 64, widx = idx >> 2, qr = idx & 3;
      const float* src = (widx == 0) ? Wq : (widx == 1) ? Wk : (widx == 2) ? Wv : Wg1;
      short* dst = (widx == 0) ? WqT : (widx == 1) ? WkT : (widx == 2) ? WvT : Wg1T;
      const float4* s4 = (const float4*)src;
      #pragma unroll
      for (int it = 0; it < 4; ++it) {
        int q = it*256 + tid; int k = qr*32 + (q >> 5), n4 = q & 31;
        float4 v = s4[k*32 + n4];
        dst[(n4*4+0)*128 + k] = (short)f2bf(v.x);
        dst[(n4*4+1)*128 + k] = (short)f2bf(v.y);
        dst[(n4*4+2)*128 + k] = (short)f2bf(v.z);
        dst[(n4*4+3)*128 + k] = (short)f2bf(v.w);
      }
    } else {
      #pragma unroll
      for (int it = 0; it < 8; ++it) {
        int idx = it*256 + tid;
        if (idx < 1808) statz[idx] = 0.f;
      }
    }
    return;
  }
  int c0 = bx*2, c1 = c0 + 1;
  // stage dense antisymmetric S as bf16
  #pragma unroll 8
  for (int it = 0; it < 64; ++it) {
    int idx = it*256 + tid; int i = idx >> 7, j = idx & 127;
    Ssh[i*LSTR + j] = (short)f2bf(fetch_asym(Sp, i, j));
  }
  if (tid < 128) {
    x0[tid] = (tid == c0) ? 1.f : 0.f;
    x1[tid] = (tid == c1) ? 1.f : 0.f;
  }
  __syncthreads();
  int i = tid >> 1, h = tid & 1;
  const short* srow = &Ssh[i*LSTR + h*64];
  for (int t = 0; t < 16; ++t) {
    float a0 = 0.f, a1 = 0.f;
    #pragma unroll
    for (int jq = 0; jq < 16; ++jq) {
      short4 sv = *(const short4*)&srow[jq*4];
      #pragma unroll
      for (int u = 0; u < 4; ++u) {
        float s = bf2f((&sv.x)[u]);
        int j = h*64 + jq*4 + u;
        a0 = fmaf(s, x0[j], a0);
        a1 = fmaf(s, x1[j], a1);
      }
    }
    a0 += __shfl_xor(a0, 1);
    a1 += __shfl_xor(a1, 1);
    __syncthreads();
    if (h == 0) {
      x0[i] = a0 + ((i == c0) ? 1.f : 0.f);
      x1[i] = a1 + ((i == c1) ? 1.f : 0.f);
    }
    __syncthreads();
  }
  if (tid < 128) {
    PTmIT[c0*128 + tid] = (short)f2bf(2.f*x0[tid] - ((tid == c0) ? 2.f : 0.f));
  } else {
    int t = tid - 128;
    PTmIT[c1*128 + t] = (short)f2bf(2.f*x1[t] - ((t == c1) ? 2.f : 0.f));
  }
  if (tid < 16) {
    int cc = tid >> 3, g = tid & 7;
    const float* xv = cc ? x1 : x0;
    int c = cc ? c1 : c0;
    float acc = 0.f;
    #pragma unroll 8
    for (int j = 0; j < 128; ++j) acc = fmaf(xv[j], Ww1[j*8 + g], acc);
    PW[c*8 + g] = 2.f*acc - Ww1[c*8 + g];
  }
}

// ---------------------------------------------------------------------------
// qkv: compute q_lin (stats+minmax, NOT stored), k_lin (stats, NOT stored),
// v (stored). A-frags direct from global fp32 feat; B-frags bf16 from L2.
template<int MODE>  // 0: stats+minmax, 1: stats, 2: store only
__device__ __forceinline__ void qkv_pass(const short* __restrict__ WT,
    const float* __restrict__ bias, float* __restrict__ Out,
    const bf16x8* af, int row0, int w, int l15, int quad, int lane,
    float* ssum, float* ssq, unsigned* ump, unsigned* umn)
{
  #pragma unroll
  for (int nt = 0; nt < 8; ++nt) {
    f32x4 ac = {0.f, 0.f, 0.f, 0.f};
    #pragma unroll
    for (int ks = 0; ks < 4; ++ks) {
      bf16x8 bf = *(const bf16x8*)&WT[(nt*16 + l15)*128 + ks*32 + quad*8];
      ac = __builtin_amdgcn_mfma_f32_16x16x32_bf16(af[ks], bf, ac, 0, 0, 0);
    }
    int col = nt*16 + l15;
    float bb = bias[col];
    float s = 0.f, s2 = 0.f, mx = -1e30f, mn = 1e30f;
    #pragma unroll
    for (int r = 0; r < 4; ++r) {
      float v = ac[r] + bb;
      if (MODE == 2) {
        int row = row0 + w*16 + quad*4 + r;
        Out[(long)row*128 + col] = v;
      } else {
        s += v; s2 = fmaf(v, v, s2);
        if (MODE == 0) { mx = fmaxf(mx, v); mn = fminf(mn, v); }
      }
    }
    if (MODE < 2) {
      s += __shfl_xor(s, 16); s += __shfl_xor(s, 32);
      s2 += __shfl_xor(s2, 16); s2 += __shfl_xor(s2, 32);
      if (MODE == 0) {
        mx = fmaxf(mx, __shfl_xor(mx, 16)); mx = fmaxf(mx, __shfl_xor(mx, 32));
        mn = fminf(mn, __shfl_xor(mn, 16)); mn = fminf(mn, __shfl_xor(mn, 32));
      }
      if (lane < 16) {
        atomicAdd(&ssum[col], s); atomicAdd(&ssq[col], s2);
        if (MODE == 0) { atomicMax(&ump[col], fenc(mx)); atomicMax(&umn[col], fenc(-mn)); }
      }
    }
  }
}

__global__ __launch_bounds__(256) void qkv_mfma(const float* __restrict__ feat,
    const short* __restrict__ WqT, const short* __restrict__ WkT, const short* __restrict__ WvT,
    const float* __restrict__ bq, const float* __restrict__ bk, const float* __restrict__ bv,
    float* __restrict__ Vv,
    float* __restrict__ statq, float* __restrict__ statk,
    unsigned* __restrict__ umaxp, unsigned* __restrict__ umaxn)
{
  __shared__ float ssum[2][128], ssq[2][128];
  __shared__ unsigned ump[128], umn[128];
  int tid = threadIdx.x, row0 = blockIdx.x * 64, seg = row0 >> 13;
  if (tid < 128) {
    ssum[0][tid] = 0.f; ssum[1][tid] = 0.f;
    ssq[0][tid] = 0.f;  ssq[1][tid] = 0.f;
    ump[tid] = 0u; umn[tid] = 0u;
  }
  __syncthreads();
  int lane = tid & 63, w = tid >> 6, l15 = lane & 15, quad = lane >> 4;
  const float4* f4 = (const float4*)feat;
  bf16x8 af[4];
  #pragma unroll
  for (int ks = 0; ks < 4; ++ks) {
    long base = (long)(row0 + w*16 + l15)*32 + ks*8 + quad*2;
    float4 a0 = f4[base], a1 = f4[base + 1];
    af[ks] = pack_bf8(a0, a1);
  }
  qkv_pass<0>(WqT, bq, nullptr, af, row0, w, l15, quad, lane, ssum[0], ssq[0], ump, umn);
  qkv_pass<1>(WkT, bk, nullptr, af, row0, w, l15, quad, lane, ssum[1], ssq[1], nullptr, nullptr);
  qkv_pass<2>(WvT, bv, Vv, af, row0, w, l15, quad, lane, nullptr, nullptr, nullptr, nullptr);
  __syncthreads();
  if (tid < 128) {
    atomicAdd(&statq[tid], ssum[0][tid]); atomicAdd(&statq[128 + tid], ssq[0][tid]);
    atomicAdd(&statk[tid], ssum[1][tid]); atomicAdd(&statk[128 + tid], ssq[1][tid]);
    atomicMax(&umaxp[seg*128 + tid], ump[tid]);
    atomicMax(&umaxn[seg*128 + tid], umn[tid]);
  }
}

// ---------------------------------------------------------------------------
// rqkw: per 32 rows — recompute q_lin/k_lin via MFMA (bitwise == qkv's),
// BN+relu (fp32 in regs), bf16 LDS round-trip to A-layout, GEMM vs (PT-I),
// exact-fp32-diag add, rope, fp32 projection -> qw/kw; plus g1 = bn(q)@Wg1top
// + gseg (gseg parallel-recomputed per block) + g1 stats.
// Waves 0,1 = q path rows 0-31; waves 2,3 = k path rows 0-31.
__global__ __launch_bounds__(256) void rqkw(
    const float* __restrict__ feat,
    const short* __restrict__ WqT, const short* __restrict__ WkT,
    const short* __restrict__ PTmIT, const short* __restrict__ Wg1T,
    const float* __restrict__ coord,
    const float* __restrict__ bq, const float* __restrict__ bk,
    const float* __restrict__ statq, const float* __restrict__ statk,
    const float* __restrict__ gq, const float* __restrict__ bnq,
    const float* __restrict__ gk, const float* __restrict__ bnk,
    const unsigned* __restrict__ umaxp, const unsigned* __restrict__ umaxn,
    const float* __restrict__ Wg1, const float* __restrict__ bg1,
    const float* __restrict__ PW, const float* __restrict__ bw1,
    float* __restrict__ qw, float* __restrict__ kw,
    float* __restrict__ g1, float* __restrict__ statg1)
{
  // arena: phase A = featS(8704B) + bnqS(8704B) + bnkS(8704B) = 26112 B
  //        phase B = xsq(16896B) + xsk(16896B) = 33792 B  (aliased)
  __shared__ __align__(16) char arena[33792];
  __shared__ float pws[1024];
  __shared__ float caq[128], cbq[128], cak[128], cbk[128];
  __shared__ float cbiasq[128], cbiask[128];
  __shared__ float gml[128], gsg[128], gpart[256];
  __shared__ float ssum[128], ssq[128];
  short* featS = (short*)arena;
  short* bnqS  = (short*)(arena + 32*LSTR*2);
  short* bnkS  = (short*)(arena + 64*LSTR*2);
  float* xsq = (float*)arena;
  float* xsk = (float*)(arena + 16896);
  int tid = threadIdx.x;
  int row0 = blockIdx.x * 32, seg = row0 >> 13;
  const float invn = 1.f / 32768.f;
  if (tid < 128) {
    float m = statq[tid]*invn, vv = fmaf(-m, m, statq[128 + tid]*invn);
    float a = rsqrtf(vv + 1e-5f) * gq[tid];
    float b = fmaf(-m, a, bnq[tid]);
    caq[tid] = a; cbq[tid] = b;
    float mx = fdec(umaxp[seg*128 + tid]);
    float mn = -fdec(umaxn[seg*128 + tid]);
    gml[tid] = fmaxf(0.f, fmaxf(fmaf(a, mx, b), fmaf(a, mn, b)));
    m = statk[tid]*invn; vv = fmaf(-m, m, statk[128 + tid]*invn);
    a = rsqrtf(vv + 1e-5f) * gk[tid];
    cak[tid] = a; cbk[tid] = fmaf(-m, a, bnk[tid]);
    cbiasq[tid] = bq[tid]; cbiask[tid] = bk[tid];
    ssum[tid] = 0.f; ssq[tid] = 0.f;
  }
  #pragma unroll
  for (int it = 0; it < 4; ++it) { int idx = tid + it*256; pws[idx] = PW[idx]; }
  {
    const float4* s4 = (const float4*)feat;
    #pragma unroll
    for (int it = 0; it < 4; ++it) {
      int q = it*256 + tid; int r = q >> 5, c4 = q & 31;
      float4 v = s4[(long)(row0 + r)*32 + c4];
      uint2 p;
      p.x = f2bf(v.x) | (f2bf(v.y) << 16);
      p.y = f2bf(v.z) | (f2bf(v.w) << 16);
      *(uint2*)&featS[r*LSTR + c4*4] = p;
    }
  }
  __syncthreads();   // S1
  // gseg partials across all 256 threads (64 MACs each)
  {
    int c = tid & 127, hf = tid >> 7;
    float acc = 0.f;
    #pragma unroll 8
    for (int j = 0; j < 64; ++j)
      acc = fmaf(gml[hf*64 + j], Wg1[(128 + hf*64 + j)*128 + c], acc);
    gpart[tid] = acc;
  }
  int lane = tid & 63, w = tid >> 6, l15 = lane & 15, quad = lane >> 4;
  bool isq = (w < 2);
  int rw = (w & 1) * 16;
  const float* ca = isq ? caq : cak;
  const float* cb = isq ? cbq : cbk;
  const float* cbias = isq ? cbiasq : cbiask;
  const short* WT = isq ? WqT : WkT;
  bf16x8 af[4];
  #pragma unroll
  for (int ks = 0; ks < 4; ++ks)
    af[ks] = *(bf16x8*)&featS[(rw + l15)*LSTR + ks*32 + quad*8];
  // GEMM1: lin = feat @ W (bitwise identical to qkv's computation)
  f32x4 lin[8];
  gemm8(WT, af, lin, l15, quad);
  // BN+relu in fp32 regs; stage bf16 C-layout for A-frag reload
  float bnl[32];
  short* bnS = isq ? bnqS : bnkS;
  #pragma unroll
  for (int nt = 0; nt < 8; ++nt) {
    int col = nt*16 + l15;
    float A = ca[col], B = cb[col], BI = cbias[col];
    #pragma unroll
    for (int r = 0; r < 4; ++r) {
      float v = fmaxf(0.f, fmaf(A, lin[nt][r] + BI, B));
      bnl[nt*4 + r] = v;
      bnS[(rw + quad*4 + r)*LSTR + col] = (short)f2bf(v);
    }
  }
  __syncthreads();   // S2: bnS + gpart complete
  if (tid < 128) gsg[tid] = gpart[tid] + gpart[128 + tid] + bg1[tid];
  bf16x8 af2[4];
  #pragma unroll
  for (int ks = 0; ks < 4; ++ks)
    af2[ks] = *(bf16x8*)&bnS[(rw + l15)*LSTR + ks*32 + quad*8];
  // GEMM2: off-diagonal rotation
  f32x4 accv[8];
  gemm8(PTmIT, af2, accv, l15, quad);
  __syncthreads();   // S3: all af2 reads done; arena becomes xs
  float* xs = isq ? xsq : xsk;
  #pragma unroll
  for (int nt = 0; nt < 8; ++nt) {
    int col = nt*16 + l15;
    #pragma unroll
    for (int r = 0; r < 4; ++r)
      xs[(rw + quad*4 + r)*132 + col] = accv[nt][r] + bnl[nt*4 + r];  // exact fp32 diag
  }
  // GEMM3 + g1 epilogue (q waves; af2 still in regs, gsg visible after S3)
  if (isq) {
    f32x4 accw[8];
    gemm8(Wg1T, af2, accw, l15, quad);
    #pragma unroll
    for (int nt = 0; nt < 8; ++nt) {
      int col = nt*16 + l15;
      float gsv = gsg[col];
      float s = 0.f, s2 = 0.f;
      #pragma unroll
      for (int r = 0; r < 4; ++r) {
        float v = accw[nt][r] + gsv;
        int row = row0 + rw + quad*4 + r;
        g1[(long)row*128 + col] = v;
        s += v; s2 = fmaf(v, v, s2);
      }
      s += __shfl_xor(s, 16); s += __shfl_xor(s, 32);
      s2 += __shfl_xor(s2, 16); s2 += __shfl_xor(s2, 32);
      if (lane < 16) { atomicAdd(&ssum[col], s); atomicAdd(&ssq[col], s2); }
    }
  }
  __syncthreads();   // S4: xs complete
  // rope: one sincos per (row, pair) applied to BOTH q and k
  #pragma unroll
  for (int it = 0; it < 8; ++it) {
    int idx = it*256 + tid;
    int r = idx >> 6, s = idx & 63;
    if (s < 63) {
      int a3 = s / 21, j = s - a3*21;
      int cr = a3*42 + j;
      float invf = exp2f((float)(2*j) * (-13.287712379549449f / 42.f));
      float ang = coord[(row0 + r)*3 + a3] * (2.0f * invf);
      float sn, co; sincosf(ang, &sn, &co);
      float fr = xsq[r*132 + cr], fi = xsq[r*132 + cr + 21];
      xsq[r*132 + cr]      = fr*co - fi*sn;
      xsq[r*132 + cr + 21] = fr*sn + fi*co;
      fr = xsk[r*132 + cr]; fi = xsk[r*132 + cr + 21];
      xsk[r*132 + cr]      = fr*co - fi*sn;
      xsk[r*132 + cr + 21] = fr*sn + fi*co;
    }
  }
  __syncthreads();   // S5
  // projection: float4 LDS reads, 4 independent accumulators
  #pragma unroll
  for (int it = 0; it < 2; ++it) {
    int idx = it*256 + tid;
    int mat = idx >> 8, r2 = (idx >> 3) & 31, g = idx & 7;
    const float* x2 = mat ? xsk : xsq;
    float a0 = 0.f, a1 = 0.f, a2 = 0.f, a3 = 0.f;
    #pragma unroll 8
    for (int i = 0; i < 128; i += 4) {
      float4 xv = *(const float4*)&x2[r2*132 + i];
      a0 = fmaf(xv.x, pws[(i+0)*8 + g], a0);
      a1 = fmaf(xv.y, pws[(i+1)*8 + g], a1);
      a2 = fmaf(xv.z, pws[(i+2)*8 + g], a2);
      a3 = fmaf(xv.w, pws[(i+3)*8 + g], a3);
    }
    float acc = (a0 + a1) + (a2 + a3) + (mat ? bw1[g] : 0.f);
    float* dst = mat ? kw : qw;
    dst[(long)(row0 + r2)*8 + g] = acc;
  }
  if (tid < 128) {
    atomicAdd(&statg1[tid], ssum[tid]);
    atomicAdd(&statg1[128 + tid], ssq[tid]);
  }
}

// ---------------------------------------------------------------------------
// mid: blocks 0-1023 gate2 body; blocks 1024-2047 hstat body.
__global__ __launch_bounds__(256) void mid(
    const float* __restrict__ g1, const float* __restrict__ statg1,
    const float* __restrict__ ggm, const float* __restrict__ bng,
    const float* __restrict__ Wg2, const float* __restrict__ bg2,
    float* __restrict__ gate,
    const float* __restrict__ kw, const float* __restrict__ qw,
    const int* __restrict__ ref, float* __restrict__ stath)
{
  __shared__ float gs[32][132];
  __shared__ float w2s[128][8];
  __shared__ float cA[128], cB[128];
  __shared__ float red[256];
  int tid = threadIdx.x;
  if (blockIdx.x < 1024) {
    int row0 = blockIdx.x * 32;
    #pragma unroll
    for (int it = 0; it < 4; ++it) { int idx = tid + it*256; w2s[idx >> 3][idx & 7] = Wg2[idx]; }
    if (tid < 128) {
      const float invn = 1.f / 32768.f;
      float m = statg1[tid]*invn, v = fmaf(-m, m, statg1[128 + tid]*invn);
      float a = rsqrtf(v + 1e-5f) * ggm[tid];
      cA[tid] = a; cB[tid] = fmaf(-m, a, bng[tid]);
    }
    #pragma unroll
    for (int it = 0; it < 4; ++it) {
      int idx = tid + it*256; int r = idx >> 5, cq = idx & 31;
      *(float4*)&gs[r][cq*4] = *(const float4*)&g1[(long)(row0 + r)*128 + cq*4];
    }
    __syncthreads();
    int r = tid >> 3, g = tid & 7;
    float acc = bg2[g];
    #pragma unroll 8
    for (int c2 = 0; c2 < 128; ++c2) {
      float act = fmaxf(0.f, fmaf(gs[r][c2], cA[c2], cB[c2]));
      acc = fmaf(act, w2s[c2][g], acc);
    }
    gate[(long)(row0 + r)*8 + g] = 1.f / (1.f + expf(-acc));
  } else {
    long base = (long)(blockIdx.x - 1024) * 4096;
    float s = 0.f, sq = 0.f;
    for (int it = 0; it < 16; ++it) {
      long idx = base + it*256 + tid;
      int n = (int)(idx >> 7); int kk = (int)((idx >> 3) & 15); int g = (int)(idx & 7);
      int r = ref[n*16 + kk];
      float h = kw[(long)r*8 + g] - qw[(long)n*8 + g];
      s += h; sq = fmaf(h, h, sq);
    }
    red[tid] = s; __syncthreads();
    for (int d = 128; d >= 8; d >>= 1) { if (tid < d) red[tid] += red[tid + d]; __syncthreads(); }
    if (tid < 8) atomicAdd(&stath[tid], red[tid]);
    __syncthreads();
    red[tid] = sq; __syncthreads();
    for (int d = 128; d >= 8; d >>= 1) { if (tid < d) red[tid] += red[tid + d]; __syncthreads(); }
    if (tid < 8) atomicAdd(&stath[8 + tid], red[tid]);
  }
}

// ---------------------------------------------------------------------------
// Final: recompute h from qw/kw gather; BN+relu -> @Ww2+bw2 -> *(1+gate)
// -> softmax(K) -> mask -> V gather
__global__ __launch_bounds__(256) void attn_out(const float* __restrict__ qw, const float* __restrict__ kw,
                                                const float* __restrict__ stath,
                                                const float* __restrict__ gw, const float* __restrict__ bnw,
                                                const float* __restrict__ Ww2, const float* __restrict__ bw2,
                                                const float* __restrict__ gate, const int* __restrict__ ref,
                                                const float* __restrict__ v, float* __restrict__ out)
{
  __shared__ float sm1[2][16][9];
  __shared__ float sm2[2][16][9];
  __shared__ int   smr[2][16];
  int tid = threadIdx.x; int rh = tid >> 7, t = tid & 127;
  int n = blockIdx.x * 2 + rh;
  int kk = t >> 3, g = t & 7;
  if (t < 16) smr[rh][t] = ref[n*16 + t];
  __syncthreads();
  const float invnk = 1.f / 524288.f;
  float m0 = stath[g]*invnk, v0 = fmaf(-m0, m0, stath[8 + g]*invnk);
  float aw = rsqrtf(v0 + 1e-5f) * gw[g];
  float bw = fmaf(-m0, aw, bnw[g]);
  int rr = smr[rh][kk];
  float h = kw[(long)rr*8 + g] - qw[(long)n*8 + g];
  sm1[rh][kk][g] = fmaxf(0.f, fmaf(h, aw, bw));
  __syncthreads();
  float acc = bw2[g];
  #pragma unroll
  for (int g2 = 0; g2 < 8; ++g2) acc = fmaf(sm1[rh][kk][g2], Ww2[g2*8 + g], acc);
  float refined = acc * (1.f + gate[(long)n*8 + g]);
  sm2[rh][kk][g] = refined;
  __syncthreads();
  float mx = -1e30f;
  #pragma unroll
  for (int k2 = 0; k2 < 16; ++k2) mx = fmaxf(mx, sm2[rh][k2][g]);
  float e = expf(refined - mx);
  sm1[rh][kk][g] = e;
  __syncthreads();
  float ssum = 0.f;
  #pragma unroll
  for (int k2 = 0; k2 < 16; ++k2) ssum += sm1[rh][k2][g];
  float mask = ((rr + 1) > 0) ? 1.f : (((rr + 1) == 0) ? 0.f : -1.f);
  float attn = e / ssum * mask;
  sm2[rh][kk][g] = attn;
  __syncthreads();
  float o = 0.f;
  #pragma unroll
  for (int k2 = 0; k2 < 16; ++k2) {
    o = fmaf(v[(long)smr[rh][k2]*128 + t], sm2[rh][k2][t >> 4], o);
  }
  out[(long)n*128 + t] = o;
}

// ---------------------------------------------------------------------------
extern "C" void kernel_launch(void* const* d_in, const int* in_sizes, int n_in,
                              void* d_out, int out_size, void* d_ws, size_t ws_size,
                              hipStream_t stream)
{
  const float* feat  = (const float*)d_in[0];
  const float* coord = (const float*)d_in[1];
  const int*   ref   = (const int*)d_in[2];
  const float* Wq  = (const float*)d_in[4];
  const float* bq  = (const float*)d_in[5];
  const float* gq  = (const float*)d_in[6];
  const float* bnq = (const float*)d_in[7];
  const float* Wk  = (const float*)d_in[8];
  const float* bk  = (const float*)d_in[9];
  const float* gk  = (const float*)d_in[10];
  const float* bnk = (const float*)d_in[11];
  const float* Wv  = (const float*)d_in[12];
  const float* bv  = (const float*)d_in[13];
  const float* Sp  = (const float*)d_in[14];
  const float* Ww1 = (const float*)d_in[15];
  const float* bw1 = (const float*)d_in[16];
  const float* gw  = (const float*)d_in[17];
  const float* bnw = (const float*)d_in[18];
  const float* Ww2 = (const float*)d_in[19];
  const float* bw2 = (const float*)d_in[20];
  const float* Wg1 = (const float*)d_in[21];
  const float* bg1 = (const float*)d_in[22];
  const float* ggm = (const float*)d_in[23];
  const float* bng = (const float*)d_in[24];
  const float* Wg2 = (const float*)d_in[25];
  const float* bg2 = (const float*)d_in[26];
  float* out = (float*)d_out;

  float* W = (float*)d_ws;
  float* PW = W + OF_PW;
  short* WqT   = (short*)(W + OF_WQT);
  short* WkT   = (short*)(W + OF_WKT);
  short* WvT   = (short*)(W + OF_WVT);
  short* Wg1T  = (short*)(W + OF_WG1T);
  short* PTmIT = (short*)(W + OF_PTMIT);
  float* G1 = W + OF_G1;
  float* Vv = W + OF_V;

  // 1: Cayley via per-column Neumann + weight bf16 transposes + stat zeroing
  cayley<<<81, 256, 0, stream>>>(Sp, Ww1, Wq, Wk, Wv, Wg1,
                                 WqT, WkT, WvT, Wg1T, PTmIT, PW, W + OF_STATQ);
  // 2: stats/minmax for q,k; store v only
  qkv_mfma<<<512, 256, 0, stream>>>(feat, WqT, WkT, WvT, bq, bk, bv, Vv,
                                    W + OF_STATQ, W + OF_STATK,
                                    (unsigned*)(W + OF_UMAXP), (unsigned*)(W + OF_UMAXN));
  // 3: recompute lin + BN + rotate + rope + project + g1(+stats)
  rqkw<<<1024, 256, 0, stream>>>(feat, WqT, WkT, PTmIT, Wg1T, coord,
                                 bq, bk,
                                 W + OF_STATQ, W + OF_STATK,
                                 gq, bnq, gk, bnk,
                                 (const unsigned*)(W + OF_UMAXP), (const unsigned*)(W + OF_UMAXN),
                                 Wg1, bg1, PW, bw1,
                                 W + OF_QW, W + OF_KW, G1, W + OF_STATG1);
  // 4: gate2 + hstat
  mid<<<2048, 256, 0, stream>>>(G1, W + OF_STATG1, ggm, bng, Wg2, bg2, W + OF_GATE,
                                W + OF_KW, W + OF_QW, ref, W + OF_STATH);
  // 5: final attention + V gather
  attn_out<<<16384, 256, 0, stream>>>(W + OF_QW, W + OF_KW, W + OF_STATH, gw, bnw, Ww2, bw2,
                                      W + OF_GATE, ref, Vv, out);
}

// Round 7
// 313.938 us; speedup vs baseline: 1.1055x; 1.1055x over previous
//
#include <hip/hip_runtime.h>
#include <math.h>

// Problem constants (fixed shapes)
#define N_PTS 32768
#define C_DIM 128
#define K_NB  16
#define G_DIM 8

// Workspace float offsets
#define OF_PW     0          // 128*8  P @ Ww1 (fp32)
#define OF_STATQ  1024       // 256 (sum, sumsq) of q_lin
#define OF_STATK  1280       // 256
#define OF_STATG1 1536       // 256
#define OF_STATH  1792       // 16
#define OF_UMAXP  1808       // 4*128 encoded max(q_lin) per seg
#define OF_UMAXN  2320       // 4*128 encoded max(-q_lin) per seg  (zero region = 1024..2832, 1808 words)
// bf16 [n][k] operands, 16384 shorts = 8192 floats each
#define OF_WQT    4096
#define OF_WKT    12288
#define OF_WVT    20480
#define OF_WG1T   28672
#define OF_PTMIT  36864
#define OF_QW     65536      // N*8
#define OF_KW     327680     // N*8
#define OF_GATE   589824     // N*8
#define OF_G1     1048576    // N*128
#define OF_V      5242880    // N*128

typedef short bf16x8 __attribute__((ext_vector_type(8)));
typedef float f32x4  __attribute__((ext_vector_type(4)));

#define LSTR 136   // bf16 LDS row stride (272 B)

__device__ __forceinline__ unsigned f2bf(float f) {
  unsigned u = __float_as_uint(f);
  return (u + 0x7fffu + ((u >> 16) & 1u)) >> 16;
}
__device__ __forceinline__ float bf2f(short s) {
  return __uint_as_float(((unsigned)(unsigned short)s) << 16);
}
__device__ __forceinline__ unsigned fenc(float f) {
  unsigned b = __float_as_uint(f);
  return (b & 0x80000000u) ? ~b : (b | 0x80000000u);
}
__device__ __forceinline__ float fdec(unsigned u) {
  unsigned b = (u & 0x80000000u) ? (u & 0x7fffffffu) : ~u;
  return __uint_as_float(b);
}
__device__ __forceinline__ bf16x8 pack_bf8(float4 a, float4 b) {
  bf16x8 r;
  r[0] = (short)f2bf(a.x); r[1] = (short)f2bf(a.y);
  r[2] = (short)f2bf(a.z); r[3] = (short)f2bf(a.w);
  r[4] = (short)f2bf(b.x); r[5] = (short)f2bf(b.y);
  r[6] = (short)f2bf(b.z); r[7] = (short)f2bf(b.w);
  return r;
}
__device__ __forceinline__ float fetch_asym(const float* M, int r, int c) {
  return (c > r) ? M[r*128 + c] : ((c < r) ? -M[c*128 + r] : 0.f);
}

// Bulk-copy a bf16 [128][128] matrix from global into LDS [128][LSTR].
// Coalesced 16B/lane; 2-way write aliasing only (free).
__device__ __forceinline__ void stageB(short* dst, const short* __restrict__ src, int tid) {
  #pragma unroll
  for (int it = 0; it < 8; ++it) {
    int q = it*256 + tid;          // 2048 chunks of 8 shorts
    int r = q >> 4, c8 = q & 15;
    *(uint4*)&dst[r*LSTR + c8*8] = *(const uint4*)&src[r*128 + c8*8];
  }
}

// MFMA over LDS-resident B: out[nt] = af @ Bl  (Bl bf16 [n][LSTR])
__device__ __forceinline__ void gemm8_lds(const short* Bl, const bf16x8* af,
                                          f32x4* out, int l15, int quad)
{
  #pragma unroll
  for (int nt = 0; nt < 8; ++nt) {
    f32x4 ac = {0.f, 0.f, 0.f, 0.f};
    #pragma unroll
    for (int ks = 0; ks < 4; ++ks) {
      bf16x8 bf = *(const bf16x8*)&Bl[(nt*16 + l15)*LSTR + ks*32 + quad*8];
      ac = __builtin_amdgcn_mfma_f32_16x16x32_bf16(af[ks], bf, ac, 0, 0, 0);
    }
    out[nt] = ac;
  }
}

// ---------------------------------------------------------------------------
// cayley: ONE kernel for all preprocessing.
//  blocks 0..63  : Neumann-solve 2 columns of (I-S)^-1 (x <- e + S x, 16 iters)
//  blocks 64..79 : Wq/Wk/Wv/Wg1top -> bf16 transposed [n][k]
//  block  80     : zero the stats region
__global__ __launch_bounds__(256) void cayley(const float* __restrict__ Sp,
    const float* __restrict__ Ww1,
    const float* __restrict__ Wq, const float* __restrict__ Wk,
    const float* __restrict__ Wv, const float* __restrict__ Wg1,
    short* __restrict__ WqT, short* __restrict__ WkT,
    short* __restrict__ WvT, short* __restrict__ Wg1T,
    short* __restrict__ PTmIT, float* __restrict__ PW,
    float* __restrict__ statz)
{
  __shared__ short Ssh[128*LSTR];
  __shared__ float x0[128], x1[128];
  int bx = blockIdx.x, tid = threadIdx.x;
  if (bx >= 64) {
    if (bx < 80) {
      int idx = bx - 64, widx = idx >> 2, qr = idx & 3;
      const float* src = (widx == 0) ? Wq : (widx == 1) ? Wk : (widx == 2) ? Wv : Wg1;
      short* dst = (widx == 0) ? WqT : (widx == 1) ? WkT : (widx == 2) ? WvT : Wg1T;
      const float4* s4 = (const float4*)src;
      #pragma unroll
      for (int it = 0; it < 4; ++it) {
        int q = it*256 + tid; int k = qr*32 + (q >> 5), n4 = q & 31;
        float4 v = s4[k*32 + n4];
        dst[(n4*4+0)*128 + k] = (short)f2bf(v.x);
        dst[(n4*4+1)*128 + k] = (short)f2bf(v.y);
        dst[(n4*4+2)*128 + k] = (short)f2bf(v.z);
        dst[(n4*4+3)*128 + k] = (short)f2bf(v.w);
      }
    } else {
      #pragma unroll
      for (int it = 0; it < 8; ++it) {
        int idx = it*256 + tid;
        if (idx < 1808) statz[idx] = 0.f;
      }
    }
    return;
  }
  int c0 = bx*2, c1 = c0 + 1;
  #pragma unroll 8
  for (int it = 0; it < 64; ++it) {
    int idx = it*256 + tid; int i = idx >> 7, j = idx & 127;
    Ssh[i*LSTR + j] = (short)f2bf(fetch_asym(Sp, i, j));
  }
  if (tid < 128) {
    x0[tid] = (tid == c0) ? 1.f : 0.f;
    x1[tid] = (tid == c1) ? 1.f : 0.f;
  }
  __syncthreads();
  int i = tid >> 1, h = tid & 1;
  const short* srow = &Ssh[i*LSTR + h*64];
  for (int t = 0; t < 16; ++t) {
    float a0 = 0.f, a1 = 0.f;
    #pragma unroll
    for (int jq = 0; jq < 16; ++jq) {
      short4 sv = *(const short4*)&srow[jq*4];
      #pragma unroll
      for (int u = 0; u < 4; ++u) {
        float s = bf2f((&sv.x)[u]);
        int j = h*64 + jq*4 + u;
        a0 = fmaf(s, x0[j], a0);
        a1 = fmaf(s, x1[j], a1);
      }
    }
    a0 += __shfl_xor(a0, 1);
    a1 += __shfl_xor(a1, 1);
    __syncthreads();
    if (h == 0) {
      x0[i] = a0 + ((i == c0) ? 1.f : 0.f);
      x1[i] = a1 + ((i == c1) ? 1.f : 0.f);
    }
    __syncthreads();
  }
  if (tid < 128) {
    PTmIT[c0*128 + tid] = (short)f2bf(2.f*x0[tid] - ((tid == c0) ? 2.f : 0.f));
  } else {
    int t = tid - 128;
    PTmIT[c1*128 + t] = (short)f2bf(2.f*x1[t] - ((t == c1) ? 2.f : 0.f));
  }
  if (tid < 16) {
    int cc = tid >> 3, g = tid & 7;
    const float* xv = cc ? x1 : x0;
    int c = cc ? c1 : c0;
    float acc = 0.f;
    #pragma unroll 8
    for (int j = 0; j < 128; ++j) acc = fmaf(xv[j], Ww1[j*8 + g], acc);
    PW[c*8 + g] = 2.f*acc - Ww1[c*8 + g];
  }
}

// ---------------------------------------------------------------------------
// qkv: 64-row blocks; A-frags from LDS-staged feat; B from LDS-staged bf16
// weights (restaged per matrix). q: stats+minmax (no store); k: stats; v: store.
__global__ __launch_bounds__(256) void qkv_mfma(const float* __restrict__ feat,
    const short* __restrict__ WqT, const short* __restrict__ WkT, const short* __restrict__ WvT,
    const float* __restrict__ bq, const float* __restrict__ bk, const float* __restrict__ bv,
    float* __restrict__ Vv,
    float* __restrict__ statq, float* __restrict__ statk,
    unsigned* __restrict__ umaxp, unsigned* __restrict__ umaxn)
{
  __shared__ short featS[64*LSTR];   // 17408 B
  __shared__ short Bbuf[128*LSTR];   // 34816 B
  __shared__ float ssum[2][128], ssq[2][128];
  __shared__ unsigned ump[128], umn[128];
  int tid = threadIdx.x, row0 = blockIdx.x * 64, seg = row0 >> 13;
  if (tid < 128) {
    ssum[0][tid] = 0.f; ssum[1][tid] = 0.f;
    ssq[0][tid] = 0.f;  ssq[1][tid] = 0.f;
    ump[tid] = 0u; umn[tid] = 0u;
  }
  {
    const float4* s4 = (const float4*)feat;
    #pragma unroll
    for (int it = 0; it < 8; ++it) {
      int q = it*256 + tid; int r = q >> 5, c4 = q & 31;
      float4 v = s4[(long)(row0 + r)*32 + c4];
      uint2 p;
      p.x = f2bf(v.x) | (f2bf(v.y) << 16);
      p.y = f2bf(v.z) | (f2bf(v.w) << 16);
      *(uint2*)&featS[r*LSTR + c4*4] = p;
    }
  }
  stageB(Bbuf, WqT, tid);
  __syncthreads();                       // S0
  int lane = tid & 63, w = tid >> 6, l15 = lane & 15, quad = lane >> 4;
  bf16x8 af[4];
  #pragma unroll
  for (int ks = 0; ks < 4; ++ks)
    af[ks] = *(bf16x8*)&featS[(w*16 + l15)*LSTR + ks*32 + quad*8];

  // ---- q: stats + minmax
  {
    f32x4 acc8[8];
    gemm8_lds(Bbuf, af, acc8, l15, quad);
    #pragma unroll
    for (int nt = 0; nt < 8; ++nt) {
      int col = nt*16 + l15;
      float bb = bq[col];
      float s = 0.f, s2 = 0.f, mx = -1e30f, mn = 1e30f;
      #pragma unroll
      for (int r = 0; r < 4; ++r) {
        float v = acc8[nt][r] + bb;
        s += v; s2 = fmaf(v, v, s2); mx = fmaxf(mx, v); mn = fminf(mn, v);
      }
      s += __shfl_xor(s, 16); s += __shfl_xor(s, 32);
      s2 += __shfl_xor(s2, 16); s2 += __shfl_xor(s2, 32);
      mx = fmaxf(mx, __shfl_xor(mx, 16)); mx = fmaxf(mx, __shfl_xor(mx, 32));
      mn = fminf(mn, __shfl_xor(mn, 16)); mn = fminf(mn, __shfl_xor(mn, 32));
      if (lane < 16) {
        atomicAdd(&ssum[0][col], s); atomicAdd(&ssq[0][col], s2);
        atomicMax(&ump[col], fenc(mx)); atomicMax(&umn[col], fenc(-mn));
      }
    }
  }
  __syncthreads();                       // S1: Bbuf reads done
  stageB(Bbuf, WkT, tid);
  __syncthreads();                       // S2
  // ---- k: stats
  {
    f32x4 acc8[8];
    gemm8_lds(Bbuf, af, acc8, l15, quad);
    #pragma unroll
    for (int nt = 0; nt < 8; ++nt) {
      int col = nt*16 + l15;
      float bb = bk[col];
      float s = 0.f, s2 = 0.f;
      #pragma unroll
      for (int r = 0; r < 4; ++r) {
        float v = acc8[nt][r] + bb;
        s += v; s2 = fmaf(v, v, s2);
      }
      s += __shfl_xor(s, 16); s += __shfl_xor(s, 32);
      s2 += __shfl_xor(s2, 16); s2 += __shfl_xor(s2, 32);
      if (lane < 16) { atomicAdd(&ssum[1][col], s); atomicAdd(&ssq[1][col], s2); }
    }
  }
  __syncthreads();                       // S3
  stageB(Bbuf, WvT, tid);
  __syncthreads();                       // S4
  // ---- v: store
  {
    f32x4 acc8[8];
    gemm8_lds(Bbuf, af, acc8, l15, quad);
    #pragma unroll
    for (int nt = 0; nt < 8; ++nt) {
      int col = nt*16 + l15;
      float bb = bv[col];
      #pragma unroll
      for (int r = 0; r < 4; ++r) {
        int row = row0 + w*16 + quad*4 + r;
        Vv[(long)row*128 + col] = acc8[nt][r] + bb;
      }
    }
  }
  __syncthreads();                       // S5
  if (tid < 128) {
    atomicAdd(&statq[tid], ssum[0][tid]); atomicAdd(&statq[128 + tid], ssq[0][tid]);
    atomicAdd(&statk[tid], ssum[1][tid]); atomicAdd(&statk[128 + tid], ssq[1][tid]);
    atomicMax(&umaxp[seg*128 + tid], ump[tid]);
    atomicMax(&umaxn[seg*128 + tid], umn[tid]);
  }
}

// ---------------------------------------------------------------------------
// rqkw: 32-row blocks. Recompute q_lin/k_lin (bitwise == qkv), BN in regs,
// rotation GEMM vs LDS-staged PTmIT, exact fp32 diag, rope, projection;
// plus g1 = bn(q)@Wg1top + gseg (per-block recompute) + stats.
// All B operands staged through one LDS buffer; arena aliased across phases.
__global__ __launch_bounds__(256) void rqkw(
    const float* __restrict__ feat,
    const short* __restrict__ WqT, const short* __restrict__ WkT,
    const short* __restrict__ PTmIT, const short* __restrict__ Wg1T,
    const float* __restrict__ coord,
    const float* __restrict__ bq, const float* __restrict__ bk,
    const float* __restrict__ statq, const float* __restrict__ statk,
    const float* __restrict__ gq, const float* __restrict__ bnq,
    const float* __restrict__ gk, const float* __restrict__ bnk,
    const unsigned* __restrict__ umaxp, const unsigned* __restrict__ umaxn,
    const float* __restrict__ Wg1, const float* __restrict__ bg1,
    const float* __restrict__ PW, const float* __restrict__ bw1,
    float* __restrict__ qw, float* __restrict__ kw,
    float* __restrict__ g1, float* __restrict__ statg1)
{
  // arena (60928 B):
  //   phase A: featS 0..8704 | bnqS 8704..17408 | bnkS 17408..26112 | Bbuf 26112..60928
  //   phase B: xsq 0..16896 | xsk 16896..33792 | pws 33792..37888 (dead Bbuf)
  __shared__ __align__(16) char arena[60928];
  __shared__ float caq[128], cbq[128], cak[128], cbk[128];  // cb* has bias folded
  __shared__ float gml[128], gsg[128];
  __shared__ float ssum[128], ssq[128];
  short* featS = (short*)arena;
  short* bnqS  = (short*)(arena + 8704);
  short* bnkS  = (short*)(arena + 17408);
  short* Bbuf  = (short*)(arena + 26112);
  float* xsq = (float*)arena;
  float* xsk = (float*)(arena + 16896);
  float* pws = (float*)(arena + 33792);
  int tid = threadIdx.x;
  int row0 = blockIdx.x * 32, seg = row0 >> 13;
  const float invn = 1.f / 32768.f;
  if (tid < 128) {
    float m = statq[tid]*invn, vv = fmaf(-m, m, statq[128 + tid]*invn);
    float a = rsqrtf(vv + 1e-5f) * gq[tid];
    float b = fmaf(-m, a, bnq[tid]);       // BN intercept (applies to lin+bias)
    caq[tid] = a; cbq[tid] = fmaf(a, bq[tid], b);   // bias folded for GEMM path
    float mx = fdec(umaxp[seg*128 + tid]);
    float mn = -fdec(umaxn[seg*128 + tid]);
    gml[tid] = fmaxf(0.f, fmaxf(fmaf(a, mx, b), fmaf(a, mn, b)));  // minmax tracked on lin+bias
    m = statk[tid]*invn; vv = fmaf(-m, m, statk[128 + tid]*invn);
    a = rsqrtf(vv + 1e-5f) * gk[tid];
    b = fmaf(-m, a, bnk[tid]);
    cak[tid] = a; cbk[tid] = fmaf(a, bk[tid], b);
    ssum[tid] = 0.f; ssq[tid] = 0.f;
  }
  {
    const float4* s4 = (const float4*)feat;
    #pragma unroll
    for (int it = 0; it < 4; ++it) {
      int q = it*256 + tid; int r = q >> 5, c4 = q & 31;
      float4 v = s4[(long)(row0 + r)*32 + c4];
      uint2 p;
      p.x = f2bf(v.x) | (f2bf(v.y) << 16);
      p.y = f2bf(v.z) | (f2bf(v.w) << 16);
      *(uint2*)&featS[r*LSTR + c4*4] = p;
    }
  }
  stageB(Bbuf, WqT, tid);
  __syncthreads();                       // S0
  int lane = tid & 63, w = tid >> 6, l15 = lane & 15, quad = lane >> 4;
  bool isq = (w < 2);
  int rw = (w & 1) * 16;
  const float* ca = isq ? caq : cak;
  const float* cb = isq ? cbq : cbk;
  bf16x8 af[4];
  #pragma unroll
  for (int ks = 0; ks < 4; ++ks)
    af[ks] = *(bf16x8*)&featS[(rw + l15)*LSTR + ks*32 + quad*8];

  float bnl[32];
  // ---- GEMM1q (q waves); k waves just hold af
  if (isq) {
    f32x4 lin[8];
    gemm8_lds(Bbuf, af, lin, l15, quad);
    #pragma unroll
    for (int nt = 0; nt < 8; ++nt) {
      int col = nt*16 + l15;
      float A = ca[col], B = cb[col];
      #pragma unroll
      for (int r = 0; r < 4; ++r) {
        float v = fmaxf(0.f, fmaf(A, lin[nt][r], B));
        bnl[nt*4 + r] = v;
        bnqS[(rw + quad*4 + r)*LSTR + col] = (short)f2bf(v);
      }
    }
  }
  __syncthreads();                       // S1: Bbuf(WqT) reads done
  stageB(Bbuf, WkT, tid);
  __syncthreads();                       // S2
  // ---- GEMM1k (k waves); q threads overlap with gseg recompute
  if (!isq) {
    f32x4 lin[8];
    gemm8_lds(Bbuf, af, lin, l15, quad);
    #pragma unroll
    for (int nt = 0; nt < 8; ++nt) {
      int col = nt*16 + l15;
      float A = ca[col], B = cb[col];
      #pragma unroll
      for (int r = 0; r < 4; ++r) {
        float v = fmaxf(0.f, fmaf(A, lin[nt][r], B));
        bnl[nt*4 + r] = v;
        bnkS[(rw + quad*4 + r)*LSTR + col] = (short)f2bf(v);
      }
    }
  } else if (tid < 128) {
    float acc = bg1[tid];
    #pragma unroll 8
    for (int j = 0; j < 128; ++j)
      acc = fmaf(gml[j], Wg1[(128 + j)*128 + tid], acc);
    gsg[tid] = acc;
  }
  __syncthreads();                       // S3: Bbuf(WkT) reads done; bnS ready
  stageB(Bbuf, PTmIT, tid);
  __syncthreads();                       // S4
  // ---- GEMM2: off-diagonal rotation (both paths)
  bf16x8 af2[4];
  {
    const short* bnS = isq ? bnqS : bnkS;
    #pragma unroll
    for (int ks = 0; ks < 4; ++ks)
      af2[ks] = *(bf16x8*)&bnS[(rw + l15)*LSTR + ks*32 + quad*8];
  }
  f32x4 accv[8];
  gemm8_lds(Bbuf, af2, accv, l15, quad);
  __syncthreads();                       // S5: Bbuf(PTmIT) reads done
  stageB(Bbuf, Wg1T, tid);
  __syncthreads();                       // S6
  // ---- GEMM3 (q waves only)
  f32x4 accw[8];
  if (isq) gemm8_lds(Bbuf, af2, accw, l15, quad);
  __syncthreads();                       // S7: all arena readers done -> xs phase
  {
    float* xs = isq ? xsq : xsk;
    #pragma unroll
    for (int nt = 0; nt < 8; ++nt) {
      int col = nt*16 + l15;
      #pragma unroll
      for (int r = 0; r < 4; ++r)
        xs[(rw + quad*4 + r)*132 + col] = accv[nt][r] + bnl[nt*4 + r];  // exact fp32 diag
    }
  }
  #pragma unroll
  for (int it = 0; it < 4; ++it) { int idx = tid + it*256; pws[idx] = PW[idx]; }
  if (isq) {
    #pragma unroll
    for (int nt = 0; nt < 8; ++nt) {
      int col = nt*16 + l15;
      float gsv = gsg[col];
      float s = 0.f, s2 = 0.f;
      #pragma unroll
      for (int r = 0; r < 4; ++r) {
        float v = accw[nt][r] + gsv;
        int row = row0 + rw + quad*4 + r;
        g1[(long)row*128 + col] = v;
        s += v; s2 = fmaf(v, v, s2);
      }
      s += __shfl_xor(s, 16); s += __shfl_xor(s, 32);
      s2 += __shfl_xor(s2, 16); s2 += __shfl_xor(s2, 32);
      if (lane < 16) { atomicAdd(&ssum[col], s); atomicAdd(&ssq[col], s2); }
    }
  }
  __syncthreads();                       // S8: xs + pws ready
  // rope: one sincos per (row, pair) applied to BOTH q and k
  #pragma unroll
  for (int it = 0; it < 8; ++it) {
    int idx = it*256 + tid;
    int r = idx >> 6, s = idx & 63;
    if (s < 63) {
      int a3 = s / 21, j = s - a3*21;
      int cr = a3*42 + j;
      float invf = exp2f((float)(2*j) * (-13.287712379549449f / 42.f));
      float ang = coord[(row0 + r)*3 + a3] * (2.0f * invf);
      float sn, co; sincosf(ang, &sn, &co);
      float fr = xsq[r*132 + cr], fi = xsq[r*132 + cr + 21];
      xsq[r*132 + cr]      = fr*co - fi*sn;
      xsq[r*132 + cr + 21] = fr*sn + fi*co;
      fr = xsk[r*132 + cr]; fi = xsk[r*132 + cr + 21];
      xsk[r*132 + cr]      = fr*co - fi*sn;
      xsk[r*132 + cr + 21] = fr*sn + fi*co;
    }
  }
  __syncthreads();                       // S9
  // projection: float4 LDS reads, 4 independent accumulators
  #pragma unroll
  for (int it = 0; it < 2; ++it) {
    int idx = it*256 + tid;
    int mat = idx >> 8, r2 = (idx >> 3) & 31, g = idx & 7;
    const float* x2 = mat ? xsk : xsq;
    float a0 = 0.f, a1 = 0.f, a2 = 0.f, a3 = 0.f;
    #pragma unroll 8
    for (int i = 0; i < 128; i += 4) {
      float4 xv = *(const float4*)&x2[r2*132 + i];
      a0 = fmaf(xv.x, pws[(i+0)*8 + g], a0);
      a1 = fmaf(xv.y, pws[(i+1)*8 + g], a1);
      a2 = fmaf(xv.z, pws[(i+2)*8 + g], a2);
      a3 = fmaf(xv.w, pws[(i+3)*8 + g], a3);
    }
    float acc = (a0 + a1) + (a2 + a3) + (mat ? bw1[g] : 0.f);
    float* dst = mat ? kw : qw;
    dst[(long)(row0 + r2)*8 + g] = acc;
  }
  if (tid < 128) {
    atomicAdd(&statg1[tid], ssum[tid]);
    atomicAdd(&statg1[128 + tid], ssq[tid]);
  }
}

// ---------------------------------------------------------------------------
// mid: blocks 0-1023 gate2 body; blocks 1024-2047 hstat body.
__global__ __launch_bounds__(256) void mid(
    const float* __restrict__ g1, const float* __restrict__ statg1,
    const float* __restrict__ ggm, const float* __restrict__ bng,
    const float* __restrict__ Wg2, const float* __restrict__ bg2,
    float* __restrict__ gate,
    const float* __restrict__ kw, const float* __restrict__ qw,
    const int* __restrict__ ref, float* __restrict__ stath)
{
  __shared__ float gs[32][132];
  __shared__ float w2s[128][8];
  __shared__ float cA[128], cB[128];
  __shared__ float red[256];
  int tid = threadIdx.x;
  if (blockIdx.x < 1024) {
    int row0 = blockIdx.x * 32;
    #pragma unroll
    for (int it = 0; it < 4; ++it) { int idx = tid + it*256; w2s[idx >> 3][idx & 7] = Wg2[idx]; }
    if (tid < 128) {
      const float invn = 1.f / 32768.f;
      float m = statg1[tid]*invn, v = fmaf(-m, m, statg1[128 + tid]*invn);
      float a = rsqrtf(v + 1e-5f) * ggm[tid];
      cA[tid] = a; cB[tid] = fmaf(-m, a, bng[tid]);
    }
    #pragma unroll
    for (int it = 0; it < 4; ++it) {
      int idx = tid + it*256; int r = idx >> 5, cq = idx & 31;
      *(float4*)&gs[r][cq*4] = *(const float4*)&g1[(long)(row0 + r)*128 + cq*4];
    }
    __syncthreads();
    int r = tid >> 3, g = tid & 7;
    float acc = bg2[g];
    #pragma unroll 8
    for (int c2 = 0; c2 < 128; ++c2) {
      float act = fmaxf(0.f, fmaf(gs[r][c2], cA[c2], cB[c2]));
      acc = fmaf(act, w2s[c2][g], acc);
    }
    gate[(long)(row0 + r)*8 + g] = 1.f / (1.f + expf(-acc));
  } else {
    long base = (long)(blockIdx.x - 1024) * 4096;
    float s = 0.f, sq = 0.f;
    for (int it = 0; it < 16; ++it) {
      long idx = base + it*256 + tid;
      int n = (int)(idx >> 7); int kk = (int)((idx >> 3) & 15); int g = (int)(idx & 7);
      int r = ref[n*16 + kk];
      float h = kw[(long)r*8 + g] - qw[(long)n*8 + g];
      s += h; sq = fmaf(h, h, sq);
    }
    red[tid] = s; __syncthreads();
    for (int d = 128; d >= 8; d >>= 1) { if (tid < d) red[tid] += red[tid + d]; __syncthreads(); }
    if (tid < 8) atomicAdd(&stath[tid], red[tid]);
    __syncthreads();
    red[tid] = sq; __syncthreads();
    for (int d = 128; d >= 8; d >>= 1) { if (tid < d) red[tid] += red[tid + d]; __syncthreads(); }
    if (tid < 8) atomicAdd(&stath[8 + tid], red[tid]);
  }
}

// ---------------------------------------------------------------------------
// Final: recompute h from qw/kw gather; BN+relu -> @Ww2+bw2 -> *(1+gate)
// -> softmax(K) -> mask -> V gather
__global__ __launch_bounds__(256) void attn_out(const float* __restrict__ qw, const float* __restrict__ kw,
                                                const float* __restrict__ stath,
                                                const float* __restrict__ gw, const float* __restrict__ bnw,
                                                const float* __restrict__ Ww2, const float* __restrict__ bw2,
                                                const float* __restrict__ gate, const int* __restrict__ ref,
                                                const float* __restrict__ v, float* __restrict__ out)
{
  __shared__ float sm1[2][16][9];
  __shared__ float sm2[2][16][9];
  __shared__ int   smr[2][16];
  int tid = threadIdx.x; int rh = tid >> 7, t = tid & 127;
  int n = blockIdx.x * 2 + rh;
  int kk = t >> 3, g = t & 7;
  if (t < 16) smr[rh][t] = ref[n*16 + t];
  __syncthreads();
  const float invnk = 1.f / 524288.f;
  float m0 = stath[g]*invnk, v0 = fmaf(-m0, m0, stath[8 + g]*invnk);
  float aw = rsqrtf(v0 + 1e-5f) * gw[g];
  float bw = fmaf(-m0, aw, bnw[g]);
  int rr = smr[rh][kk];
  float h = kw[(long)rr*8 + g] - qw[(long)n*8 + g];
  sm1[rh][kk][g] = fmaxf(0.f, fmaf(h, aw, bw));
  __syncthreads();
  float acc = bw2[g];
  #pragma unroll
  for (int g2 = 0; g2 < 8; ++g2) acc = fmaf(sm1[rh][kk][g2], Ww2[g2*8 + g], acc);
  float refined = acc * (1.f + gate[(long)n*8 + g]);
  sm2[rh][kk][g] = refined;
  __syncthreads();
  float mx = -1e30f;
  #pragma unroll
  for (int k2 = 0; k2 < 16; ++k2) mx = fmaxf(mx, sm2[rh][k2][g]);
  float e = expf(refined - mx);
  sm1[rh][kk][g] = e;
  __syncthreads();
  float ssum = 0.f;
  #pragma unroll
  for (int k2 = 0; k2 < 16; ++k2) ssum += sm1[rh][k2][g];
  float mask = ((rr + 1) > 0) ? 1.f : (((rr + 1) == 0) ? 0.f : -1.f);
  float attn = e / ssum * mask;
  sm2[rh][kk][g] = attn;
  __syncthreads();
  float o = 0.f;
  #pragma unroll
  for (int k2 = 0; k2 < 16; ++k2) {
    o = fmaf(v[(long)smr[rh][k2]*128 + t], sm2[rh][k2][t >> 4], o);
  }
  out[(long)n*128 + t] = o;
}

// ---------------------------------------------------------------------------
extern "C" void kernel_launch(void* const* d_in, const int* in_sizes, int n_in,
                              void* d_out, int out_size, void* d_ws, size_t ws_size,
                              hipStream_t stream)
{
  const float* feat  = (const float*)d_in[0];
  const float* coord = (const float*)d_in[1];
  const int*   ref   = (const int*)d_in[2];
  const float* Wq  = (const float*)d_in[4];
  const float* bq  = (const float*)d_in[5];
  const float* gq  = (const float*)d_in[6];
  const float* bnq = (const float*)d_in[7];
  const float* Wk  = (const float*)d_in[8];
  const float* bk  = (const float*)d_in[9];
  const float* gk  = (const float*)d_in[10];
  const float* bnk = (const float*)d_in[11];
  const float* Wv  = (const float*)d_in[12];
  const float* bv  = (const float*)d_in[13];
  const float* Sp  = (const float*)d_in[14];
  const float* Ww1 = (const float*)d_in[15];
  const float* bw1 = (const float*)d_in[16];
  const float* gw  = (const float*)d_in[17];
  const float* bnw = (const float*)d_in[18];
  const float* Ww2 = (const float*)d_in[19];
  const float* bw2 = (const float*)d_in[20];
  const float* Wg1 = (const float*)d_in[21];
  const float* bg1 = (const float*)d_in[22];
  const float* ggm = (const float*)d_in[23];
  const float* bng = (const float*)d_in[24];
  const float* Wg2 = (const float*)d_in[25];
  const float* bg2 = (const float*)d_in[26];
  float* out = (float*)d_out;

  float* W = (float*)d_ws;
  float* PW = W + OF_PW;
  short* WqT   = (short*)(W + OF_WQT);
  short* WkT   = (short*)(W + OF_WKT);
  short* WvT   = (short*)(W + OF_WVT);
  short* Wg1T  = (short*)(W + OF_WG1T);
  short* PTmIT = (short*)(W + OF_PTMIT);
  float* G1 = W + OF_G1;
  float* Vv = W + OF_V;

  // 1: Cayley via per-column Neumann + weight bf16 transposes + stat zeroing
  cayley<<<81, 256, 0, stream>>>(Sp, Ww1, Wq, Wk, Wv, Wg1,
                                 WqT, WkT, WvT, Wg1T, PTmIT, PW, W + OF_STATQ);
  // 2: stats/minmax for q,k; store v only (LDS-staged B)
  qkv_mfma<<<512, 256, 0, stream>>>(feat, WqT, WkT, WvT, bq, bk, bv, Vv,
                                    W + OF_STATQ, W + OF_STATK,
                                    (unsigned*)(W + OF_UMAXP), (unsigned*)(W + OF_UMAXN));
  // 3: recompute lin + BN + rotate + rope + project + g1(+stats) (LDS-staged B)
  rqkw<<<1024, 256, 0, stream>>>(feat, WqT, WkT, PTmIT, Wg1T, coord,
                                 bq, bk,
                                 W + OF_STATQ, W + OF_STATK,
                                 gq, bnq, gk, bnk,
                                 (const unsigned*)(W + OF_UMAXP), (const unsigned*)(W + OF_UMAXN),
                                 Wg1, bg1, PW, bw1,
                                 W + OF_QW, W + OF_KW, G1, W + OF_STATG1);
  // 4: gate2 + hstat
  mid<<<2048, 256, 0, stream>>>(G1, W + OF_STATG1, ggm, bng, Wg2, bg2, W + OF_GATE,
                                W + OF_KW, W + OF_QW, ref, W + OF_STATH);
  // 5: final attention + V gather
  attn_out<<<16384, 256, 0, stream>>>(W + OF_QW, W + OF_KW, W + OF_STATH, gw, bnw, Ww2, bw2,
                                      W + OF_GATE, ref, Vv, out);
}